// Round 3
// baseline (292.027 us; speedup 1.0000x reference)
//
#include <hip/hip_runtime.h>

#define MDIM 4096
#define NDIM 1024
#define KDIM 512
#define TSTEPS 50

__global__ __launch_bounds__(256) void zero_tot_kernel(float* __restrict__ tot) {
    int i = blockIdx.x * 256 + threadIdx.x;
    if (i < MDIM) tot[i] = 0.0f;
}

// 1024 one-wave blocks: 64x64 tile, 8x8 micro-tile, BK=32, no barriers.
// LDS read ratio: per wave-k 4 ds_read_b128 for 64 FMAs (1.5x per-CU cycle
// ratio, vs 3.0x for the R2 4x4 scheme). All reads conflict-free:
//   A: [row][kquad XOR (row>>3)] -> 8 bcast addrs on 8 distinct bank-quads
//   B: [k][n] -> 8 bcast addrs, 2-way bank alias (free)
__global__ __launch_bounds__(64, 1) void snn_fused_kernel(
    const float* __restrict__ A,    // x [4096,512]
    const float* __restrict__ B,    // W_proj [512,1024]
    const float* __restrict__ bias, // b_proj [1024]
    float* __restrict__ agg,        // d_out[0 : 4096*1024]
    float* __restrict__ tot)        // d_out[4096*1024 : +4096]
{
    __shared__ __align__(16) float sA[2][64 * 32];  // [row][kq swz] 8 KB each
    __shared__ __align__(16) float sB[2][32 * 64];  // [k][n]        8 KB each

    const int tid = threadIdx.x;
    const int tx  = tid & 7;    // 8 col-groups (8 cols each)
    const int ty  = tid >> 3;   // 8 row-groups (8 rows each)

    // XCD swizzle: each XCD gets 128 consecutive tile indices; bm-major so an
    // XCD's slice shares A panels and B (2 MB) stays L2-resident.
    const int b   = blockIdx.x;
    const int swz = (b & 7) * 128 + (b >> 3);   // bijective, 1024 % 8 == 0
    const int bm  = swz >> 4;   // 64 tiles in M
    const int bn  = swz & 15;   // 16 tiles in N
    const int m0  = bm * 64;
    const int n0  = bn * 64;

    // staging mapping (64 threads)
    const int as_ = tid >> 3;   // A row within 8-row group
    const int aq  = tid & 7;    // A k-quad
    const int bkr = tid >> 4;   // B k within 4-row group
    const int bc  = tid & 15;   // B col-quad

    const float* gA = A + (size_t)(m0 + as_) * KDIM + aq * 4;
    const float* gB = B + (size_t)bkr * NDIM + n0 + bc * 4;

    float4 pa[8], pb[8];
    #pragma unroll
    for (int i = 0; i < 8; ++i) pa[i] = *(const float4*)(gA + i * 8 * KDIM);
    #pragma unroll
    for (int i = 0; i < 8; ++i) pb[i] = *(const float4*)(gB + i * 4 * NDIM);

    // stage chunk 0 -> buf 0 (single wave: no barrier, lgkmcnt orders DS ops)
    #pragma unroll
    for (int i = 0; i < 8; ++i)
        *(float4*)&sA[0][(i * 8 + as_) * 32 + ((aq ^ i) << 2)] = pa[i];
    #pragma unroll
    for (int i = 0; i < 8; ++i)
        *(float4*)&sB[0][(bkr + 4 * i) * 64 + bc * 4] = pb[i];

    float acc[8][8];
    #pragma unroll
    for (int r = 0; r < 8; ++r)
        #pragma unroll
        for (int c = 0; c < 8; ++c) acc[r][c] = 0.0f;

    #pragma unroll 1
    for (int ch = 0; ch < 16; ++ch) {
        const int buf = ch & 1;
        if (ch < 15) {  // issue next-chunk global loads early; write LDS late
            #pragma unroll
            for (int i = 0; i < 8; ++i)
                pa[i] = *(const float4*)(gA + (ch + 1) * 32 + i * 8 * KDIM);
            #pragma unroll
            for (int i = 0; i < 8; ++i)
                pb[i] = *(const float4*)(gB + (size_t)(ch + 1) * 32 * NDIM + i * 4 * NDIM);
        }
        const float* lA = sA[buf];
        const float* lB = sB[buf];
        #pragma unroll
        for (int j = 0; j < 8; ++j) {   // 8 k-quads of 4
            float a4[8][4];
            const float* pA = lA + ty * 256 + (((j ^ ty) & 7) << 2);
            #pragma unroll
            for (int r = 0; r < 8; ++r) {
                float4 v = *(const float4*)(pA + r * 32);
                a4[r][0] = v.x; a4[r][1] = v.y; a4[r][2] = v.z; a4[r][3] = v.w;
            }
            #pragma unroll
            for (int kk = 0; kk < 4; ++kk) {
                float4 v0 = *(const float4*)(lB + (4 * j + kk) * 64 + tx * 8);
                float4 v1 = *(const float4*)(lB + (4 * j + kk) * 64 + tx * 8 + 4);
                float bl[8] = {v0.x, v0.y, v0.z, v0.w, v1.x, v1.y, v1.z, v1.w};
                #pragma unroll
                for (int r = 0; r < 8; ++r)
                    #pragma unroll
                    for (int c = 0; c < 8; ++c)
                        acc[r][c] = fmaf(a4[r][kk], bl[c], acc[r][c]);
            }
        }
        if (ch < 15) {  // stage next chunk into the other buffer
            const int nb = buf ^ 1;
            #pragma unroll
            for (int i = 0; i < 8; ++i)
                *(float4*)&sA[nb][(i * 8 + as_) * 32 + ((aq ^ i) << 2)] = pa[i];
            #pragma unroll
            for (int i = 0; i < 8; ++i)
                *(float4*)&sB[nb][(bkr + 4 * i) * 64 + bc * 4] = pb[i];
        }
    }

    // bias for this thread's 8 cols
    float4 bv0 = *(const float4*)(bias + n0 + tx * 8);
    float4 bv1 = *(const float4*)(bias + n0 + tx * 8 + 4);
    float cb[8] = {bv0.x, bv0.y, bv0.z, bv0.w, bv1.x, bv1.y, bv1.z, bv1.w};

    // LIF recurrence: both layers identical -> simulate once.
    // spk_t == reset_{t+1}; fold reset: mem = fma(beta, mem, sp ? c-1 : c)
    #pragma unroll
    for (int r = 0; r < 8; ++r) {
        float c[8], c1[8], mem[8];
        int cnt[8];
        bool sp[8];
        #pragma unroll
        for (int j = 0; j < 8; ++j) {
            c[j]   = acc[r][j] + cb[j];
            c1[j]  = c[j] - 1.0f;
            mem[j] = 0.0f;
            cnt[j] = 0;
            sp[j]  = false;
        }
        #pragma unroll 1
        for (int t = 0; t < TSTEPS; ++t) {
            #pragma unroll
            for (int j = 0; j < 8; ++j) {
                mem[j] = fmaf(0.95f, mem[j], sp[j] ? c1[j] : c[j]);
                sp[j]  = mem[j] > 1.0f;
                cnt[j] += sp[j] ? 1 : 0;
            }
        }
        const int row = m0 + ty * 8 + r;
        float4 o0 = make_float4((float)cnt[0], (float)cnt[1], (float)cnt[2], (float)cnt[3]);
        float4 o1 = make_float4((float)cnt[4], (float)cnt[5], (float)cnt[6], (float)cnt[7]);
        *(float4*)&agg[(size_t)row * NDIM + n0 + tx * 8]     = o0;
        *(float4*)&agg[(size_t)row * NDIM + n0 + tx * 8 + 4] = o1;
        // tot partial: integer counts, exact in fp32, order-independent
        int rs = cnt[0] + cnt[1] + cnt[2] + cnt[3] + cnt[4] + cnt[5] + cnt[6] + cnt[7];
        rs += __shfl_xor(rs, 1);   // reduce over tx (lane bits 0..2, same ty)
        rs += __shfl_xor(rs, 2);
        rs += __shfl_xor(rs, 4);
        if (tx == 0) atomicAdd(&tot[row], 2.0f * (float)rs);
    }
}

extern "C" void kernel_launch(void* const* d_in, const int* in_sizes, int n_in,
                              void* d_out, int out_size, void* d_ws, size_t ws_size,
                              hipStream_t stream) {
    const float* x = (const float*)d_in[0];
    const float* W = (const float*)d_in[1];
    const float* b = (const float*)d_in[2];
    float* agg = (float*)d_out;
    float* tot = agg + (size_t)MDIM * NDIM;

    zero_tot_kernel<<<(MDIM + 255) / 256, 256, 0, stream>>>(tot);
    snn_fused_kernel<<<(MDIM / 64) * (NDIM / 64), 64, 0, stream>>>(x, W, b, agg, tot);
}

// Round 4
// 196.695 us; speedup vs baseline: 1.4847x; 1.4847x over previous
//
#include <hip/hip_runtime.h>
#include <stdint.h>

#define MDIM 4096
#define NDIM 1024
#define KDIM 512
#define BK   32
#define NCH  (KDIM / BK)   // 16
#define TSTEPS 50

typedef const __attribute__((address_space(1))) void cgv_t;
typedef __attribute__((address_space(3))) void lv_t;

__device__ __forceinline__ void gload16(const float* g, float* s) {
    // global -> LDS direct, 16B per lane; LDS dest is wave-uniform base + lane*16
    __builtin_amdgcn_global_load_lds((cgv_t*)g, (lv_t*)s, 16, 0, 0);
}

__global__ __launch_bounds__(256) void zero_tot_kernel(float* __restrict__ tot) {
    int i = blockIdx.x * 256 + threadIdx.x;
    if (i < MDIM) tot[i] = 0.0f;
}

// 256 threads (4 waves), 128x128 tile, 8x8 micro-tile, BK=32.
// Staging: global_load_lds (zero staging VGPRs), 2-buffer, counted vmcnt(8),
// raw s_barrier (loads stay in flight across barriers).
// sA[row][p]: p = kquad ^ ((row>>2)&3)  (XOR swizzle, inverse applied on the
// global SOURCE address so the LDS dest stays linear). sB[k][n] natural.
__global__ __launch_bounds__(256, 1) void snn_fused_kernel(
    const float* __restrict__ A,    // x [4096,512]
    const float* __restrict__ B,    // W_proj [512,1024]
    const float* __restrict__ bias, // b_proj [1024]
    float* __restrict__ agg,        // d_out[0 : 4096*1024]
    float* __restrict__ tot)        // d_out[4096*1024 : +4096]
{
    __shared__ __align__(16) float sA[2][128 * 32];  // 16 KB per buf
    __shared__ __align__(16) float sB[2][32 * 128];  // 16 KB per buf

    const int tid = threadIdx.x;
    const int l   = tid & 63;
    const int w   = tid >> 6;     // wave id 0..3
    const int tx  = tid & 15;     // 16 col groups
    const int ty  = tid >> 4;     // 16 row groups
    const int tyl = ty & 3;       // A-read swizzle key (distinct within a wave)

    // XCD swizzle: XCD x gets bm in [x*4, x*4+4) x all bn -> 1MB A-slice + 2MB B per XCD L2
    const int b   = blockIdx.x;
    const int swz = (b & 7) * 32 + (b >> 3);
    const int bm  = swz >> 3;    // 32 M-tiles
    const int bn  = swz & 7;     // 8 N-tiles
    const int m0  = bm * 128;
    const int n0  = bn * 128;

    // per-thread staging sources (4 insts each for A and B per chunk)
    const float* srcA[4];
    const float* srcB[4];
    int dA[4], dB[4];
    #pragma unroll
    for (int i = 0; i < 4; ++i) {
        int row = w * 32 + i * 8 + (l >> 3);            // A row within tile
        int p   = (l & 7) ^ ((row >> 2) & 3);           // inverse-swizzled source chunk
        srcA[i] = A + (size_t)(m0 + row) * KDIM + p * 4;
        dA[i]   = (w * 32 + i * 8) * 32;                // wave-uniform LDS float offset
        int k   = w * 8 + i * 2 + (l >> 5);             // B k-row within chunk
        srcB[i] = B + (size_t)k * NDIM + n0 + (l & 31) * 4;
        dB[i]   = (w * 8 + i * 2) * 128;
    }

#define STAGE(buf, ch) do {                                                   \
    _Pragma("unroll") for (int i_ = 0; i_ < 4; ++i_)                          \
        gload16(srcA[i_] + (ch) * BK, &sA[buf][dA[i_]]);                      \
    _Pragma("unroll") for (int i_ = 0; i_ < 4; ++i_)                          \
        gload16(srcB[i_] + (size_t)(ch) * BK * NDIM, &sB[buf][dB[i_]]);       \
} while (0)

    STAGE(0, 0);
    STAGE(1, 1);

    float acc[8][8];
    #pragma unroll
    for (int r = 0; r < 8; ++r)
        #pragma unroll
        for (int c = 0; c < 8; ++c) acc[r][c] = 0.0f;

    #pragma unroll 1
    for (int ch = 0; ch < NCH; ++ch) {
        if (ch < NCH - 1) asm volatile("s_waitcnt vmcnt(8)" ::: "memory");
        else              asm volatile("s_waitcnt vmcnt(0)" ::: "memory");
        __builtin_amdgcn_s_barrier();
        asm volatile("" ::: "memory");
        const float* lA = sA[ch & 1];
        const float* lB = sB[ch & 1];
        #pragma unroll
        for (int j = 0; j < 8; ++j) {      // 8 k-quads
            float a[8][4];
            const float* pa = lA + ty * 128 + ((j ^ tyl) << 2);
            #pragma unroll
            for (int r = 0; r < 4; ++r) {  // rows ty*4+r
                float4 v = *(const float4*)(pa + r * 32);
                a[r][0] = v.x; a[r][1] = v.y; a[r][2] = v.z; a[r][3] = v.w;
            }
            #pragma unroll
            for (int r = 0; r < 4; ++r) {  // rows 64+ty*4+r
                float4 v = *(const float4*)(pa + 64 * 32 + r * 32);
                a[4 + r][0] = v.x; a[4 + r][1] = v.y; a[4 + r][2] = v.z; a[4 + r][3] = v.w;
            }
            #pragma unroll
            for (int kk = 0; kk < 4; ++kk) {
                float4 v0 = *(const float4*)(lB + (4 * j + kk) * 128 + tx * 4);
                float4 v1 = *(const float4*)(lB + (4 * j + kk) * 128 + tx * 4 + 64);
                float bl[8] = {v0.x, v0.y, v0.z, v0.w, v1.x, v1.y, v1.z, v1.w};
                #pragma unroll
                for (int r = 0; r < 8; ++r)
                    #pragma unroll
                    for (int c = 0; c < 8; ++c)
                        acc[r][c] = fmaf(a[r][kk], bl[c], acc[r][c]);
            }
        }
        __builtin_amdgcn_s_barrier();      // all waves done reading buf[ch&1]
        asm volatile("" ::: "memory");
        if (ch + 2 < NCH) STAGE(ch & 1, ch + 2);
    }

    // bias for this thread's 8 cols (issued after all counted vmcnt waits)
    float4 bb0 = *(const float4*)(bias + n0 + tx * 4);
    float4 bb1 = *(const float4*)(bias + n0 + tx * 4 + 64);
    float cb[8] = {bb0.x, bb0.y, bb0.z, bb0.w, bb1.x, bb1.y, bb1.z, bb1.w};

    // LIF recurrence: both layers identical -> simulate once.
    // spk_t == reset_{t+1}; fold reset: mem = fma(beta, mem, sp ? c-1 : c)
    #pragma unroll
    for (int rr = 0; rr < 8; ++rr) {
        float c[8], c1[8], mem[8];
        int cnt[8];
        bool sp[8];
        #pragma unroll
        for (int j = 0; j < 8; ++j) {
            c[j]   = acc[rr][j] + cb[j];
            c1[j]  = c[j] - 1.0f;
            mem[j] = 0.0f;
            cnt[j] = 0;
            sp[j]  = false;
        }
        #pragma unroll 1
        for (int t = 0; t < TSTEPS; ++t) {
            #pragma unroll
            for (int j = 0; j < 8; ++j) {
                mem[j] = fmaf(0.95f, mem[j], sp[j] ? c1[j] : c[j]);
                sp[j]  = mem[j] > 1.0f;
                cnt[j] += sp[j] ? 1 : 0;
            }
        }
        const int row = m0 + ((rr < 4) ? (ty * 4 + rr) : (64 + ty * 4 + rr - 4));
        float4 o0 = make_float4((float)cnt[0], (float)cnt[1], (float)cnt[2], (float)cnt[3]);
        float4 o1 = make_float4((float)cnt[4], (float)cnt[5], (float)cnt[6], (float)cnt[7]);
        *(float4*)&agg[(size_t)row * NDIM + n0 + tx * 4]      = o0;
        *(float4*)&agg[(size_t)row * NDIM + n0 + tx * 4 + 64] = o1;
        // tot partial: integer counts, exact in fp32, order-independent
        int rs = cnt[0] + cnt[1] + cnt[2] + cnt[3] + cnt[4] + cnt[5] + cnt[6] + cnt[7];
        rs += __shfl_xor(rs, 1);   // reduce over tx (16 lanes share a row)
        rs += __shfl_xor(rs, 2);
        rs += __shfl_xor(rs, 4);
        rs += __shfl_xor(rs, 8);
        if (tx == 0) atomicAdd(&tot[row], 2.0f * (float)rs);
    }
}

extern "C" void kernel_launch(void* const* d_in, const int* in_sizes, int n_in,
                              void* d_out, int out_size, void* d_ws, size_t ws_size,
                              hipStream_t stream) {
    const float* x = (const float*)d_in[0];
    const float* W = (const float*)d_in[1];
    const float* b = (const float*)d_in[2];
    float* agg = (float*)d_out;
    float* tot = agg + (size_t)MDIM * NDIM;

    zero_tot_kernel<<<(MDIM + 255) / 256, 256, 0, stream>>>(tot);
    snn_fused_kernel<<<(MDIM / 128) * (NDIM / 128), 256, 0, stream>>>(x, W, b, agg, tot);
}

// Round 5
// 101.210 us; speedup vs baseline: 2.8854x; 1.9434x over previous
//
#include <hip/hip_runtime.h>
#include <stdint.h>

#define MDIM 4096
#define NDIM 1024
#define KDIM 512
#define BK   32
#define NCH  (KDIM / BK)   // 16
#define TSTEPS 50

typedef const __attribute__((address_space(1))) void cgv_t;
typedef __attribute__((address_space(3))) void lv_t;

__device__ __forceinline__ void gload16(const float* g, float* s) {
    // global -> LDS direct, 16B per lane; LDS dest is wave-uniform base + lane*16
    __builtin_amdgcn_global_load_lds((cgv_t*)g, (lv_t*)s, 16, 0, 0);
}

__global__ __launch_bounds__(256) void zero_tot_kernel(float* __restrict__ tot) {
    int i = blockIdx.x * 256 + threadIdx.x;
    if (i < MDIM) tot[i] = 0.0f;
}

// 256 threads (4 waves), 128x128 tile, 8x8 micro-tile, BK=32.
// Staging: global_load_lds (zero staging VGPRs), 2-buffer, counted vmcnt(8),
// raw s_barrier. sA[row][p]: p = kquad ^ ((row>>2)&3) (inverse swizzle applied
// on the global SOURCE; LDS dest linear). sB[k][n] natural (2-way = free).
// j-loop is unroll-1 to bound live LDS-load registers (R4 spilled at 256 VGPR
// because full unroll let the scheduler hoist 8 iterations of a4[8][4]).
__global__ __launch_bounds__(256, 1) void snn_fused_kernel(
    const float* __restrict__ A,    // x [4096,512]
    const float* __restrict__ B,    // W_proj [512,1024]
    const float* __restrict__ bias, // b_proj [1024]
    float* __restrict__ agg,        // d_out[0 : 4096*1024]
    float* __restrict__ tot)        // d_out[4096*1024 : +4096]
{
    __shared__ __align__(16) float sA[2][128 * 32];  // 16 KB per buf
    __shared__ __align__(16) float sB[2][32 * 128];  // 16 KB per buf

    const int tid = threadIdx.x;
    const int l   = tid & 63;
    const int w   = tid >> 6;     // wave id 0..3
    const int tx  = tid & 15;     // 16 col groups
    const int ty  = tid >> 4;     // 16 row groups
    const int tyl = ty & 3;       // A-read swizzle key (distinct within a wave)

    // XCD swizzle: XCD x gets bm in [x*4, x*4+4) x all bn -> 1MB A-slice + 2MB B per XCD L2
    const int b   = blockIdx.x;
    const int swz = (b & 7) * 32 + (b >> 3);
    const int bm  = swz >> 3;    // 32 M-tiles
    const int bn  = swz & 7;     // 8 N-tiles
    const int m0  = bm * 128;
    const int n0  = bn * 128;

    // per-thread staging sources (4 insts each for A and B per chunk)
    const float* srcA[4];
    const float* srcB[4];
    int dA[4], dB[4];
    #pragma unroll
    for (int i = 0; i < 4; ++i) {
        int row = w * 32 + i * 8 + (l >> 3);            // A row within tile
        int p   = (l & 7) ^ ((row >> 2) & 3);           // inverse-swizzled source chunk
        srcA[i] = A + (size_t)(m0 + row) * KDIM + p * 4;
        dA[i]   = (w * 32 + i * 8) * 32;                // wave-uniform LDS float offset
        int k   = w * 8 + i * 2 + (l >> 5);             // B k-row within chunk
        srcB[i] = B + (size_t)k * NDIM + n0 + (l & 31) * 4;
        dB[i]   = (w * 8 + i * 2) * 128;
    }

#define STAGE(buf, ch) do {                                                   \
    _Pragma("unroll") for (int i_ = 0; i_ < 4; ++i_)                          \
        gload16(srcA[i_] + (ch) * BK, &sA[buf][dA[i_]]);                      \
    _Pragma("unroll") for (int i_ = 0; i_ < 4; ++i_)                          \
        gload16(srcB[i_] + (size_t)(ch) * BK * NDIM, &sB[buf][dB[i_]]);       \
} while (0)

    STAGE(0, 0);
    STAGE(1, 1);

    float acc[8][8];
    #pragma unroll
    for (int r = 0; r < 8; ++r)
        #pragma unroll
        for (int c = 0; c < 8; ++c) acc[r][c] = 0.0f;

    #pragma unroll 1
    for (int ch = 0; ch < NCH; ++ch) {
        if (ch < NCH - 1) asm volatile("s_waitcnt vmcnt(8)" ::: "memory");
        else              asm volatile("s_waitcnt vmcnt(0)" ::: "memory");
        __builtin_amdgcn_s_barrier();
        asm volatile("" ::: "memory");
        const float* lA = sA[ch & 1] + ty * 128;
        const float* lB = sB[ch & 1] + tx * 4;
        #pragma unroll 1
        for (int j = 0; j < 8; ++j) {      // 8 k-quads; unroll-1 bounds liveness
            float a4[8][4];
            const float* pa = lA + (((j ^ tyl) & 7) << 2);
            #pragma unroll
            for (int r = 0; r < 4; ++r) {  // rows ty*4+r
                float4 v = *(const float4*)(pa + r * 32);
                a4[r][0] = v.x; a4[r][1] = v.y; a4[r][2] = v.z; a4[r][3] = v.w;
            }
            #pragma unroll
            for (int r = 0; r < 4; ++r) {  // rows 64+ty*4+r
                float4 v = *(const float4*)(pa + 64 * 32 + r * 32);
                a4[4 + r][0] = v.x; a4[4 + r][1] = v.y; a4[4 + r][2] = v.z; a4[4 + r][3] = v.w;
            }
            const float* pb = lB + j * 4 * 128;
            #pragma unroll
            for (int kk = 0; kk < 4; ++kk) {
                float4 v0 = *(const float4*)(pb + kk * 128);
                float4 v1 = *(const float4*)(pb + kk * 128 + 64);
                float bl[8] = {v0.x, v0.y, v0.z, v0.w, v1.x, v1.y, v1.z, v1.w};
                #pragma unroll
                for (int r = 0; r < 8; ++r)
                    #pragma unroll
                    for (int c = 0; c < 8; ++c)
                        acc[r][c] = fmaf(a4[r][kk], bl[c], acc[r][c]);
            }
        }
        __builtin_amdgcn_s_barrier();      // all waves done reading buf[ch&1]
        asm volatile("" ::: "memory");
        if (ch + 2 < NCH) STAGE(ch & 1, ch + 2);
    }

    // bias for this thread's 8 cols (after all counted vmcnt waits)
    float4 bb0 = *(const float4*)(bias + n0 + tx * 4);
    float4 bb1 = *(const float4*)(bias + n0 + tx * 4 + 64);
    float cb[8] = {bb0.x, bb0.y, bb0.z, bb0.w, bb1.x, bb1.y, bb1.z, bb1.w};

    // LIF recurrence: both layers identical -> simulate once.
    // spk_t == reset_{t+1}; fold reset: mem = fma(beta, mem, sp ? c-1 : c)
    #pragma unroll
    for (int rr = 0; rr < 8; ++rr) {
        float c[8], c1[8], mem[8];
        int cnt[8];
        bool sp[8];
        #pragma unroll
        for (int j = 0; j < 8; ++j) {
            c[j]   = acc[rr][j] + cb[j];
            c1[j]  = c[j] - 1.0f;
            mem[j] = 0.0f;
            cnt[j] = 0;
            sp[j]  = false;
        }
        #pragma unroll 1
        for (int t = 0; t < TSTEPS; ++t) {
            #pragma unroll
            for (int j = 0; j < 8; ++j) {
                mem[j] = fmaf(0.95f, mem[j], sp[j] ? c1[j] : c[j]);
                sp[j]  = mem[j] > 1.0f;
                cnt[j] += sp[j] ? 1 : 0;
            }
        }
        const int row = m0 + ((rr < 4) ? (ty * 4 + rr) : (64 + ty * 4 + rr - 4));
        float4 o0 = make_float4((float)cnt[0], (float)cnt[1], (float)cnt[2], (float)cnt[3]);
        float4 o1 = make_float4((float)cnt[4], (float)cnt[5], (float)cnt[6], (float)cnt[7]);
        *(float4*)&agg[(size_t)row * NDIM + n0 + tx * 4]      = o0;
        *(float4*)&agg[(size_t)row * NDIM + n0 + tx * 4 + 64] = o1;
        // tot partial: integer counts, exact in fp32, order-independent
        int rs = cnt[0] + cnt[1] + cnt[2] + cnt[3] + cnt[4] + cnt[5] + cnt[6] + cnt[7];
        rs += __shfl_xor(rs, 1);   // reduce over tx (16 lanes share a row)
        rs += __shfl_xor(rs, 2);
        rs += __shfl_xor(rs, 4);
        rs += __shfl_xor(rs, 8);
        if (tx == 0) atomicAdd(&tot[row], 2.0f * (float)rs);
        __builtin_amdgcn_sched_barrier(0);  // sequence rr blocks: cap epilogue liveness
    }
}

extern "C" void kernel_launch(void* const* d_in, const int* in_sizes, int n_in,
                              void* d_out, int out_size, void* d_ws, size_t ws_size,
                              hipStream_t stream) {
    const float* x = (const float*)d_in[0];
    const float* W = (const float*)d_in[1];
    const float* b = (const float*)d_in[2];
    float* agg = (float*)d_out;
    float* tot = agg + (size_t)MDIM * NDIM;

    zero_tot_kernel<<<(MDIM + 255) / 256, 256, 0, stream>>>(tot);
    snn_fused_kernel<<<(MDIM / 128) * (NDIM / 128), 256, 0, stream>>>(x, W, b, agg, tot);
}

// Round 6
// 100.022 us; speedup vs baseline: 2.9196x; 1.0119x over previous
//
#include <hip/hip_runtime.h>
#include <stdint.h>

#define MDIM 4096
#define NDIM 1024
#define KDIM 512
#define BK   32
#define NCH  (KDIM / BK)   // 16
#define TSTEPS 50

typedef const __attribute__((address_space(1))) void cgv_t;
typedef __attribute__((address_space(3))) void lv_t;

__device__ __forceinline__ void gload16(const float* g, float* s) {
    __builtin_amdgcn_global_load_lds((cgv_t*)g, (lv_t*)s, 16, 0, 0);
}

__global__ __launch_bounds__(256) void zero_tot_kernel(float* __restrict__ tot) {
    int i = blockIdx.x * 256 + threadIdx.x;
    if (i < MDIM) tot[i] = 0.0f;
}

// 256 threads (4 waves), 128x128 tile, 8x8 micro-tile, BK=32.
// Structural occupancy is 1 wave/SIMD (65536 threads @ 64 out/thread), so LDS
// latency must be hidden by ILP: manual 2-deep software pipeline over k-quads
// (load quad j+1 while FMA-ing quad j). Named buffer pairs, compile-time
// indices only; unroll-1 pair loop caps hoist depth at 2 (R4 spilled at 8).
__global__ __launch_bounds__(256, 1) void snn_fused_kernel(
    const float* __restrict__ A,    // x [4096,512]
    const float* __restrict__ B,    // W_proj [512,1024]
    const float* __restrict__ bias, // b_proj [1024]
    float* __restrict__ agg,        // d_out[0 : 4096*1024]
    float* __restrict__ tot)        // d_out[4096*1024 : +4096]
{
    __shared__ __align__(16) float sA[2][128 * 32];
    __shared__ __align__(16) float sB[2][32 * 128];

    const int tid = threadIdx.x;
    const int l   = tid & 63;
    const int w   = tid >> 6;
    const int tx  = tid & 15;
    const int ty  = tid >> 4;
    const int tyl = ty & 3;

    const int b   = blockIdx.x;
    const int swz = (b & 7) * 32 + (b >> 3);
    const int bm  = swz >> 3;
    const int bn  = swz & 7;
    const int m0  = bm * 128;
    const int n0  = bn * 128;

    const float* srcA[4];
    const float* srcB[4];
    int dA[4], dB[4];
    #pragma unroll
    for (int i = 0; i < 4; ++i) {
        int row = w * 32 + i * 8 + (l >> 3);
        int p   = (l & 7) ^ ((row >> 2) & 3);
        srcA[i] = A + (size_t)(m0 + row) * KDIM + p * 4;
        dA[i]   = (w * 32 + i * 8) * 32;
        int k   = w * 8 + i * 2 + (l >> 5);
        srcB[i] = B + (size_t)k * NDIM + n0 + (l & 31) * 4;
        dB[i]   = (w * 8 + i * 2) * 128;
    }

#define STAGE(buf, ch) do {                                                   \
    _Pragma("unroll") for (int i_ = 0; i_ < 4; ++i_)                          \
        gload16(srcA[i_] + (ch) * BK, &sA[buf][dA[i_]]);                      \
    _Pragma("unroll") for (int i_ = 0; i_ < 4; ++i_)                          \
        gload16(srcB[i_] + (size_t)(ch) * BK * NDIM, &sB[buf][dB[i_]]);       \
} while (0)

// load one k-quad's operands into register buffers (all reg indices static)
#define LOADJ(j, aR, bR) do {                                                 \
    const float* pa_ = lA + ((((j) ^ tyl) & 7) << 2);                         \
    _Pragma("unroll") for (int r_ = 0; r_ < 4; ++r_) {                        \
        float4 v_ = *(const float4*)(pa_ + r_ * 32);                          \
        aR[r_][0] = v_.x; aR[r_][1] = v_.y; aR[r_][2] = v_.z; aR[r_][3] = v_.w; \
        float4 u_ = *(const float4*)(pa_ + 2048 + r_ * 32);                   \
        aR[4+r_][0] = u_.x; aR[4+r_][1] = u_.y; aR[4+r_][2] = u_.z; aR[4+r_][3] = u_.w; \
    }                                                                         \
    const float* pb_ = lB + (j) * 512;                                        \
    _Pragma("unroll") for (int k_ = 0; k_ < 4; ++k_) {                        \
        float4 v_ = *(const float4*)(pb_ + k_ * 128);                         \
        bR[k_][0] = v_.x; bR[k_][1] = v_.y; bR[k_][2] = v_.z; bR[k_][3] = v_.w; \
        float4 u_ = *(const float4*)(pb_ + k_ * 128 + 64);                    \
        bR[k_][4] = u_.x; bR[k_][5] = u_.y; bR[k_][6] = u_.z; bR[k_][7] = u_.w; \
    }                                                                         \
} while (0)

#define FMAJ(aR, bR) do {                                                     \
    _Pragma("unroll") for (int kk_ = 0; kk_ < 4; ++kk_)                       \
        _Pragma("unroll") for (int r_ = 0; r_ < 8; ++r_)                      \
            _Pragma("unroll") for (int c_ = 0; c_ < 8; ++c_)                  \
                acc[r_][c_] = fmaf(aR[r_][kk_], bR[kk_][c_], acc[r_][c_]);    \
} while (0)

    STAGE(0, 0);
    STAGE(1, 1);

    float acc[8][8];
    #pragma unroll
    for (int r = 0; r < 8; ++r)
        #pragma unroll
        for (int c = 0; c < 8; ++c) acc[r][c] = 0.0f;

    #pragma unroll 1
    for (int ch = 0; ch < NCH; ++ch) {
        if (ch < NCH - 1) asm volatile("s_waitcnt vmcnt(8)" ::: "memory");
        else              asm volatile("s_waitcnt vmcnt(0)" ::: "memory");
        __builtin_amdgcn_s_barrier();
        asm volatile("" ::: "memory");
        const float* lA = sA[ch & 1] + ty * 128;
        const float* lB = sB[ch & 1] + tx * 4;

        float aP[8][4], bP[4][8], aQ[8][4], bQ[4][8];
        LOADJ(0, aP, bP);
        #pragma unroll 1
        for (int jj = 0; jj < 3; ++jj) {          // pairs (0,1),(2,3),(4,5)
            const int j0 = 2 * jj;
            LOADJ(j0 + 1, aQ, bQ);                // in flight during FMAJ(P)
            FMAJ(aP, bP);
            LOADJ(j0 + 2, aP, bP);                // in flight during FMAJ(Q)
            FMAJ(aQ, bQ);
        }
        LOADJ(7, aQ, bQ);                         // tail pair (6,7)
        FMAJ(aP, bP);
        FMAJ(aQ, bQ);

        __builtin_amdgcn_s_barrier();
        asm volatile("" ::: "memory");
        if (ch + 2 < NCH) STAGE(ch & 1, ch + 2);
    }

    float4 bb0 = *(const float4*)(bias + n0 + tx * 4);
    float4 bb1 = *(const float4*)(bias + n0 + tx * 4 + 64);
    float cb[8] = {bb0.x, bb0.y, bb0.z, bb0.w, bb1.x, bb1.y, bb1.z, bb1.w};

    // LIF recurrence: both layers identical -> simulate once.
    // spk_t == reset_{t+1}; fold reset: mem = fma(beta, mem, sp ? c-1 : c)
    #pragma unroll
    for (int rr = 0; rr < 8; ++rr) {
        float c[8], c1[8], mem[8];
        int cnt[8];
        bool sp[8];
        #pragma unroll
        for (int j = 0; j < 8; ++j) {
            c[j]   = acc[rr][j] + cb[j];
            c1[j]  = c[j] - 1.0f;
            mem[j] = 0.0f;
            cnt[j] = 0;
            sp[j]  = false;
        }
        #pragma unroll 1
        for (int t = 0; t < TSTEPS; ++t) {
            #pragma unroll
            for (int j = 0; j < 8; ++j) {
                mem[j] = fmaf(0.95f, mem[j], sp[j] ? c1[j] : c[j]);
                sp[j]  = mem[j] > 1.0f;
                cnt[j] += sp[j] ? 1 : 0;
            }
        }
        const int row = m0 + ((rr < 4) ? (ty * 4 + rr) : (64 + ty * 4 + rr - 4));
        float4 o0 = make_float4((float)cnt[0], (float)cnt[1], (float)cnt[2], (float)cnt[3]);
        float4 o1 = make_float4((float)cnt[4], (float)cnt[5], (float)cnt[6], (float)cnt[7]);
        *(float4*)&agg[(size_t)row * NDIM + n0 + tx * 4]      = o0;
        *(float4*)&agg[(size_t)row * NDIM + n0 + tx * 4 + 64] = o1;
        int rs = cnt[0] + cnt[1] + cnt[2] + cnt[3] + cnt[4] + cnt[5] + cnt[6] + cnt[7];
        rs += __shfl_xor(rs, 1);
        rs += __shfl_xor(rs, 2);
        rs += __shfl_xor(rs, 4);
        rs += __shfl_xor(rs, 8);
        if (tx == 0) atomicAdd(&tot[row], 2.0f * (float)rs);
        __builtin_amdgcn_sched_barrier(0);
    }
}

extern "C" void kernel_launch(void* const* d_in, const int* in_sizes, int n_in,
                              void* d_out, int out_size, void* d_ws, size_t ws_size,
                              hipStream_t stream) {
    const float* x = (const float*)d_in[0];
    const float* W = (const float*)d_in[1];
    const float* b = (const float*)d_in[2];
    float* agg = (float*)d_out;
    float* tot = agg + (size_t)MDIM * NDIM;

    zero_tot_kernel<<<(MDIM + 255) / 256, 256, 0, stream>>>(tot);
    snn_fused_kernel<<<(MDIM / 128) * (NDIM / 128), 256, 0, stream>>>(x, W, b, agg, tot);
}

// Round 7
// 89.569 us; speedup vs baseline: 3.2604x; 1.1167x over previous
//
#include <hip/hip_runtime.h>
#include <stdint.h>

#define MDIM 4096
#define NDIM 1024
#define KDIM 512
#define BK   32
#define NCH  (KDIM / BK)   // 16
#define TSTEPS 50

typedef const __attribute__((address_space(1))) void cgv_t;
typedef __attribute__((address_space(3))) void lv_t;

__device__ __forceinline__ void gload16(const float* g, float* s) {
    __builtin_amdgcn_global_load_lds((cgv_t*)g, (lv_t*)s, 16, 0, 0);
}

__global__ __launch_bounds__(256) void zero_tot_kernel(float* __restrict__ tot) {
    int i = blockIdx.x * 256 + threadIdx.x;
    if (i < MDIM) tot[i] = 0.0f;
}

// 512 threads (8 waves = 2/SIMD), 128x128 tile, 4x8 micro-tile (32 out/thread).
// LDS wall: 12 b128/quad/wave x 8 quads x 16 chunks x 8 waves = 12288 b128/CU
// x 12cyc = 61us; VALU ~37us/SIMD -> LDS-bound with 2-wave TLP to hide latency.
// (R5/R6 at 8x8 = 1 wave/SIMD was latency-exposed at 118us despite a 41us wall;
//  R2 at 4x4 = 4/SIMD sat exactly on its 82us wall.)
__global__ __launch_bounds__(512, 1) void snn_fused_kernel(
    const float* __restrict__ A,    // x [4096,512]
    const float* __restrict__ B,    // W_proj [512,1024]
    const float* __restrict__ bias, // b_proj [1024]
    float* __restrict__ agg,        // d_out[0 : 4096*1024]
    float* __restrict__ tot)        // d_out[4096*1024 : +4096]
{
    __shared__ __align__(16) float sA[2][128 * 32];  // [row][swz quad]
    __shared__ __align__(16) float sB[2][32 * 128];  // [k][n] natural

    const int tid = threadIdx.x;
    const int w   = tid >> 6;     // wave 0..7
    const int tx  = tid & 15;     // 16 col groups: cols tx*4 and tx*4+64
    const int ty  = tid >> 4;     // 32 row groups: rows ty*4+r
    const int tyk = ty & 3;       // A swizzle key (4 distinct per wave)

    // XCD swizzle (bijective, 256 = 8 x 32)
    const int b   = blockIdx.x;
    const int swz = (b & 7) * 32 + (b >> 3);
    const int bm  = swz >> 3;
    const int bn  = swz & 7;
    const int m0  = bm * 128;
    const int n0  = bn * 128;

    // staging: 2 sweeps each for A (128x32) and B (32x128); dest linear,
    // source pre-inverse-swizzled for A (both-sides-or-neither).
    const float* srcA[2];
    const float* srcB[2];
    int dst[2];
    #pragma unroll
    for (int i = 0; i < 2; ++i) {
        int arow = i * 64 + (tid >> 3);
        int q    = (tid & 7) ^ ((tid >> 5) & 3);   // (arow>>2)&3 == (tid>>5)&3
        srcA[i]  = A + (size_t)(m0 + arow) * KDIM + q * 4;
        int k    = i * 16 + (tid >> 5);
        srcB[i]  = B + (size_t)k * NDIM + n0 + (tid & 31) * 4;
        dst[i]   = i * 2048 + w * 256;             // wave-uniform base (+l*16B)
    }

#define STAGE(buf, ch) do {                                                   \
    _Pragma("unroll") for (int i_ = 0; i_ < 2; ++i_)                          \
        gload16(srcA[i_] + (ch) * BK, &sA[buf][dst[i_]]);                     \
    _Pragma("unroll") for (int i_ = 0; i_ < 2; ++i_)                          \
        gload16(srcB[i_] + (size_t)(ch) * BK * NDIM, &sB[buf][dst[i_]]);      \
} while (0)

// one k-quad: A 4 b128 (4 rows, 4-way broadcast, swizzled banks),
//             B 8 b128 (R5's proven 2-way-free tx*4 / +64 pattern)
#define LOADJ(j, aR, bR) do {                                                 \
    const float* pa_ = lA + ((((j) ^ tyk) & 7) << 2);                         \
    _Pragma("unroll") for (int r_ = 0; r_ < 4; ++r_) {                        \
        float4 v_ = *(const float4*)(pa_ + r_ * 32);                          \
        aR[r_][0] = v_.x; aR[r_][1] = v_.y; aR[r_][2] = v_.z; aR[r_][3] = v_.w; \
    }                                                                         \
    const float* pb_ = lB + (j) * 512;                                        \
    _Pragma("unroll") for (int k_ = 0; k_ < 4; ++k_) {                        \
        float4 v_ = *(const float4*)(pb_ + k_ * 128);                         \
        bR[k_][0] = v_.x; bR[k_][1] = v_.y; bR[k_][2] = v_.z; bR[k_][3] = v_.w; \
        float4 u_ = *(const float4*)(pb_ + k_ * 128 + 64);                    \
        bR[k_][4] = u_.x; bR[k_][5] = u_.y; bR[k_][6] = u_.z; bR[k_][7] = u_.w; \
    }                                                                         \
} while (0)

#define FMAJ(aR, bR) do {                                                     \
    _Pragma("unroll") for (int kk_ = 0; kk_ < 4; ++kk_)                       \
        _Pragma("unroll") for (int r_ = 0; r_ < 4; ++r_)                      \
            _Pragma("unroll") for (int c_ = 0; c_ < 8; ++c_)                  \
                acc[r_][c_] = fmaf(aR[r_][kk_], bR[kk_][c_], acc[r_][c_]);    \
} while (0)

    STAGE(0, 0);
    STAGE(1, 1);

    float acc[4][8];
    #pragma unroll
    for (int r = 0; r < 4; ++r)
        #pragma unroll
        for (int c = 0; c < 8; ++c) acc[r][c] = 0.0f;

    #pragma unroll 1
    for (int ch = 0; ch < NCH; ++ch) {
        if (ch < NCH - 1) asm volatile("s_waitcnt vmcnt(4)" ::: "memory");
        else              asm volatile("s_waitcnt vmcnt(0)" ::: "memory");
        __builtin_amdgcn_s_barrier();
        asm volatile("" ::: "memory");
        const float* lA = sA[ch & 1] + ty * 128;   // row base (ty*4 rows * 32)
        const float* lB = sB[ch & 1] + tx * 4;

        float aP[4][4], bP[4][8], aQ[4][4], bQ[4][8];
        LOADJ(0, aP, bP);
        #pragma unroll 1
        for (int jj = 0; jj < 3; ++jj) {           // pairs (0,1),(2,3),(4,5)
            const int j0 = 2 * jj;
            LOADJ(j0 + 1, aQ, bQ);                 // in flight during FMAJ(P)
            FMAJ(aP, bP);
            LOADJ(j0 + 2, aP, bP);                 // in flight during FMAJ(Q)
            FMAJ(aQ, bQ);
        }
        LOADJ(7, aQ, bQ);                          // tail pair (6,7)
        FMAJ(aP, bP);
        FMAJ(aQ, bQ);

        __builtin_amdgcn_s_barrier();
        asm volatile("" ::: "memory");
        if (ch + 2 < NCH) STAGE(ch & 1, ch + 2);
    }

    float4 bb0 = *(const float4*)(bias + n0 + tx * 4);
    float4 bb1 = *(const float4*)(bias + n0 + tx * 4 + 64);
    float cb[8] = {bb0.x, bb0.y, bb0.z, bb0.w, bb1.x, bb1.y, bb1.z, bb1.w};

    // LIF recurrence: both layers identical -> simulate once.
    // spk_t == reset_{t+1}; fold reset: mem = fma(beta, mem, sp ? c-1 : c)
    #pragma unroll
    for (int rr = 0; rr < 4; ++rr) {
        float c[8], c1[8], mem[8];
        int cnt[8];
        bool sp[8];
        #pragma unroll
        for (int j = 0; j < 8; ++j) {
            c[j]   = acc[rr][j] + cb[j];
            c1[j]  = c[j] - 1.0f;
            mem[j] = 0.0f;
            cnt[j] = 0;
            sp[j]  = false;
        }
        #pragma unroll 1
        for (int t = 0; t < TSTEPS; ++t) {
            #pragma unroll
            for (int j = 0; j < 8; ++j) {
                mem[j] = fmaf(0.95f, mem[j], sp[j] ? c1[j] : c[j]);
                sp[j]  = mem[j] > 1.0f;
                cnt[j] += sp[j] ? 1 : 0;
            }
        }
        const int row = m0 + ty * 4 + rr;
        float4 o0 = make_float4((float)cnt[0], (float)cnt[1], (float)cnt[2], (float)cnt[3]);
        float4 o1 = make_float4((float)cnt[4], (float)cnt[5], (float)cnt[6], (float)cnt[7]);
        *(float4*)&agg[(size_t)row * NDIM + n0 + tx * 4]      = o0;
        *(float4*)&agg[(size_t)row * NDIM + n0 + tx * 4 + 64] = o1;
        // tot partial: integer counts, exact in fp32, order-independent
        int rs = cnt[0] + cnt[1] + cnt[2] + cnt[3] + cnt[4] + cnt[5] + cnt[6] + cnt[7];
        rs += __shfl_xor(rs, 1);   // reduce over tx (16 lanes per row group)
        rs += __shfl_xor(rs, 2);
        rs += __shfl_xor(rs, 4);
        rs += __shfl_xor(rs, 8);
        if (tx == 0) atomicAdd(&tot[row], 2.0f * (float)rs);
        __builtin_amdgcn_sched_barrier(0);  // sequence rr blocks: cap liveness
    }
}

extern "C" void kernel_launch(void* const* d_in, const int* in_sizes, int n_in,
                              void* d_out, int out_size, void* d_ws, size_t ws_size,
                              hipStream_t stream) {
    const float* x = (const float*)d_in[0];
    const float* W = (const float*)d_in[1];
    const float* b = (const float*)d_in[2];
    float* agg = (float*)d_out;
    float* tot = agg + (size_t)MDIM * NDIM;

    zero_tot_kernel<<<(MDIM + 255) / 256, 256, 0, stream>>>(tot);
    snn_fused_kernel<<<(MDIM / 128) * (NDIM / 128), 512, 0, stream>>>(x, W, b, agg, tot);
}